// Round 12
// baseline (197.616 us; speedup 1.0000x reference)
//
#include <hip/hip_runtime.h>
#include <cstddef>

#define HID 128
#define LN_EPS 1e-5f
#define GROWS 8
#define WTP 144   // Wt LDS row pitch in shorts: 288 B = 16B-aligned rows
#define PDEG 64   // padded CSR slots per node

typedef unsigned int uint32;
typedef __attribute__((ext_vector_type(8))) short short8;
typedef __attribute__((ext_vector_type(4))) float f32x4;

__device__ __forceinline__ float wave_sum(float v) {
#pragma unroll
  for (int o = 32; o > 0; o >>= 1) v += __shfl_xor(v, o, 64);
  return v;
}

__device__ __forceinline__ uint32 bf16_rne(float x) {
  uint32 u = __float_as_uint(x);
  u += 0x7fffu + ((u >> 16) & 1u);
  return u >> 16;
}

__device__ __forceinline__ uint32 pack_bf2(float x, float y) {
  uint32 ux = __float_as_uint(x);
  uint32 uy = __float_as_uint(y);
  ux += 0x7fffu + ((ux >> 16) & 1u);
  uy += 0x7fffu + ((uy >> 16) & 1u);
  return (ux >> 16) | (uy & 0xffff0000u);
}

__device__ __forceinline__ void acc8(float* a, uint4 u) {
  a[0] += __uint_as_float(u.x << 16);
  a[1] += __uint_as_float(u.x & 0xffff0000u);
  a[2] += __uint_as_float(u.y << 16);
  a[3] += __uint_as_float(u.y & 0xffff0000u);
  a[4] += __uint_as_float(u.z << 16);
  a[5] += __uint_as_float(u.z & 0xffff0000u);
  a[6] += __uint_as_float(u.w << 16);
  a[7] += __uint_as_float(u.w & 0xffff0000u);
}

// fused: zero cnt (first zb blocks) + transpose W->bf16 for all 3 layers
extern "C" __global__ void k_setup(int* __restrict__ cnt, int N, int zb,
                                   const float* __restrict__ W0, const float* __restrict__ W1,
                                   const float* __restrict__ W2, unsigned short* __restrict__ wt) {
  int bx = blockIdx.x;
  if (bx < zb) {
    int i = bx * 256 + threadIdx.x;
    if (i < N) cnt[i] = 0;
  } else {
    int i = (bx - zb) * 256 + threadIdx.x;
    if (i < 3 * HID * HID) {
      int l = i >> 14, r = i & 16383;
      int n = r >> 7, k = r & 127;
      const float* W = (l == 0) ? W0 : ((l == 1) ? W1 : W2);
      wt[i] = (unsigned short)bf16_rne(W[k * HID + n]);
    }
  }
}

extern "C" __global__ void k_deg(const int* __restrict__ dst, int* __restrict__ deg, int E) {
  int i = blockIdx.x * blockDim.x + threadIdx.x;
  if (i < E) atomicAdd(&deg[dst[i]], 1);
}

extern "C" __global__ void k_dinv(const int* __restrict__ cnt, float* __restrict__ dinv, int N) {
  int i = blockIdx.x * blockDim.x + threadIdx.x;
  if (i < N) dinv[i] = rsqrtf((float)cnt[i] + 1.0f);
}

// XCD-partitioned padded-CSR fill: csrc[d*PDEG + pos] = src, cnt[d]++.
extern "C" __global__ void k_fill_p(const int* __restrict__ src, const int* __restrict__ dst,
                                    int* __restrict__ cnt, int* __restrict__ csrc,
                                    int E, int N) {
  int part = blockIdx.x & 7;
  int grp = blockIdx.x >> 3;
  int ngrp = gridDim.x >> 3;
  int lo = (int)((long long)N * part >> 3);
  int hi = (int)((long long)N * (part + 1) >> 3);
  for (int i = grp * blockDim.x + threadIdx.x; i < E; i += ngrp * blockDim.x) {
    int d = dst[i];
    if (d >= lo && d < hi) {
      int pos = atomicAdd(&cnt[d], 1);
      if (pos < PDEG) csrc[(size_t)d * PDEG + pos] = src[i];
    }
  }
}

// MFMA GEMM, 128-row blocks: gb[r][c-pair] = bf16(dinv[r] * sum_k x[r][k]*W[k][c])
// 4 waves, each owns 2 row-tiles of 16 (rows wv*32 .. wv*32+31). Wt staged once/block.
template <bool BF>
__global__ __launch_bounds__(256) void k_gemm_t(
    const void* __restrict__ xin, const unsigned short* __restrict__ wt,
    const int* __restrict__ cnt, uint32* __restrict__ gb, int N) {
  __shared__ unsigned short Wt[HID * WTP];
  __shared__ float dv_s[128];
  int tid = threadIdx.x, lane = tid & 63, wv = tid >> 6;
  int r0 = blockIdx.x * 128;
  int nr = min(128, N - r0);
  for (int i = tid; i < 2048; i += 256) {
    short8 v = *(const short8*)(wt + i * 8);
    int n = i >> 4, k0 = (i & 15) * 8;
    *(short8*)&Wt[n * WTP + k0] = v;
  }
  if (tid < 128) {
    int rr = min(r0 + tid, N - 1);
    dv_s[tid] = rsqrtf((float)cnt[rr] + 1.0f);
  }
  int kb = (lane >> 4) * 8;
  short8 a[2][4];
#pragma unroll
  for (int t = 0; t < 2; ++t) {
    int arow = r0 + wv * 32 + t * 16 + (lane & 15);
    int arow_c = min(arow, N - 1);
    if (BF) {
      const uint32* x32 = (const uint32*)xin;
      const uint32* rp = x32 + (size_t)arow_c * 64 + (kb >> 1);
#pragma unroll
      for (int q = 0; q < 4; ++q) a[t][q] = *(const short8*)(rp + q * 16);
    } else {
      const float* xf = (const float*)xin;
      const float* rp = xf + (size_t)arow_c * HID + kb;
#pragma unroll
      for (int q = 0; q < 4; ++q) {
        float4 f0 = *(const float4*)(rp + q * 32);
        float4 f1 = *(const float4*)(rp + q * 32 + 4);
        short8 tt;
        tt[0] = (short)bf16_rne(f0.x);
        tt[1] = (short)bf16_rne(f0.y);
        tt[2] = (short)bf16_rne(f0.z);
        tt[3] = (short)bf16_rne(f0.w);
        tt[4] = (short)bf16_rne(f1.x);
        tt[5] = (short)bf16_rne(f1.y);
        tt[6] = (short)bf16_rne(f1.z);
        tt[7] = (short)bf16_rne(f1.w);
        a[t][q] = tt;
      }
    }
  }
  __syncthreads();
  int bn = lane & 15;
#pragma unroll
  for (int c = 0; c < 8; ++c) {
    const unsigned short* wr = &Wt[(c * 16 + bn) * WTP + kb];
    short8 b0 = *(const short8*)(wr + 0);
    short8 b1 = *(const short8*)(wr + 32);
    short8 b2 = *(const short8*)(wr + 64);
    short8 b3 = *(const short8*)(wr + 96);
#pragma unroll
    for (int t = 0; t < 2; ++t) {
      f32x4 acc = {0.f, 0.f, 0.f, 0.f};
      acc = __builtin_amdgcn_mfma_f32_16x16x32_bf16(a[t][0], b0, acc, 0, 0, 0);
      acc = __builtin_amdgcn_mfma_f32_16x16x32_bf16(a[t][1], b1, acc, 0, 0, 0);
      acc = __builtin_amdgcn_mfma_f32_16x16x32_bf16(a[t][2], b2, acc, 0, 0, 0);
      acc = __builtin_amdgcn_mfma_f32_16x16x32_bf16(a[t][3], b3, acc, 0, 0, 0);
#pragma unroll
      for (int reg = 0; reg < 4; ++reg) {
        float v = acc[reg];
        float p = __shfl_xor(v, 1, 64);
        int row = wv * 32 + t * 16 + (lane >> 4) * 4 + reg;
        if (!(lane & 1) && row < nr) {
          float dvv = dv_s[row];
          gb[(size_t)(r0 + row) * 64 + (c * 8 + (bn >> 1))] = pack_bf2(v * dvv, p * dvv);
        }
      }
    }
  }
}

// wide-gather agg with idx-prefetch + MLP-4 + dual accumulators.
// wave = 1 node, 4 groups x 16 lanes; lane preloads csrc[w*64+lane];
// 16-edge blocks issue 4 independent uint4 row-gathers; indices via full-wave __shfl.
// mode 0: out_bf = packed bf16 LN(relu(h)); mode 3: out0 = h fp32, out1 = relu(h) fp32
extern "C" __global__ __launch_bounds__(256) void k_agg_bf(
    const uint32* __restrict__ gb, const int* __restrict__ cnt, const int* __restrict__ csrc,
    const float* __restrict__ bias, const float* __restrict__ gamma,
    const float* __restrict__ beta,
    uint32* __restrict__ out_bf, float* __restrict__ out0, float* __restrict__ out1,
    int N, int mode) {
  int w = (int)((blockIdx.x * blockDim.x + threadIdx.x) >> 6);
  int lane = threadIdx.x & 63;
  if (w >= N) return;
  int g = lane >> 4, c = lane & 15;
  int rawdeg = cnt[w];
  int deg = min(rawdeg, PDEG);
  int myidx = (lane < deg) ? csrc[(size_t)w * PDEG + lane] : 0;
  const uint4* gbp = (const uint4*)gb;  // row r chunk c at [r*16 + c]
  float accA[8], accB[8];
  {  // self term, counted once (group 0) -> A; B zeroed
    uint4 u = gbp[(size_t)w * 16 + c];
    float m = (g == 0) ? 1.f : 0.f;
    accA[0] = m * __uint_as_float(u.x << 16);
    accA[1] = m * __uint_as_float(u.x & 0xffff0000u);
    accA[2] = m * __uint_as_float(u.y << 16);
    accA[3] = m * __uint_as_float(u.y & 0xffff0000u);
    accA[4] = m * __uint_as_float(u.z << 16);
    accA[5] = m * __uint_as_float(u.z & 0xffff0000u);
    accA[6] = m * __uint_as_float(u.w << 16);
    accA[7] = m * __uint_as_float(u.w & 0xffff0000u);
#pragma unroll
    for (int i = 0; i < 8; ++i) accB[i] = 0.f;
  }
  int j = 0;
  for (; j + 16 <= deg; j += 16) {
    int s0 = __shfl(myidx, j + g, 64);
    int s1 = __shfl(myidx, j + 4 + g, 64);
    int s2 = __shfl(myidx, j + 8 + g, 64);
    int s3 = __shfl(myidx, j + 12 + g, 64);
    uint4 u0 = gbp[(size_t)s0 * 16 + c];
    uint4 u1 = gbp[(size_t)s1 * 16 + c];
    uint4 u2 = gbp[(size_t)s2 * 16 + c];
    uint4 u3 = gbp[(size_t)s3 * 16 + c];
    acc8(accA, u0);
    acc8(accB, u1);
    acc8(accA, u2);
    acc8(accB, u3);
  }
  for (; j + 4 <= deg; j += 4) {
    int s = __shfl(myidx, j + g, 64);
    uint4 u = gbp[(size_t)s * 16 + c];
    acc8(accA, u);
  }
  if (j < deg) {  // wave-uniform entry: shfl runs with ALL lanes active
    int s = __shfl(myidx, j + g, 64);
    if (g < deg - j) {  // only the load/acc is masked
      uint4 u = gbp[(size_t)s * 16 + c];
      acc8(accB, u);
    }
  }
  float acc[8];
#pragma unroll
  for (int i = 0; i < 8; ++i) acc[i] = accA[i] + accB[i];
  // cross-group reduce: every lane then holds full sums for its 8 cols
#pragma unroll
  for (int i = 0; i < 8; ++i) {
    acc[i] += __shfl_xor(acc[i], 16, 64);
    acc[i] += __shfl_xor(acc[i], 32, 64);
  }
  float dv = rsqrtf((float)rawdeg + 1.0f);
  float4 bb0 = *(const float4*)(bias + c * 8);
  float4 bb1 = *(const float4*)(bias + c * 8 + 4);
  float h[8];
  h[0] = fmaf(acc[0], dv, bb0.x);
  h[1] = fmaf(acc[1], dv, bb0.y);
  h[2] = fmaf(acc[2], dv, bb0.z);
  h[3] = fmaf(acc[3], dv, bb0.w);
  h[4] = fmaf(acc[4], dv, bb1.x);
  h[5] = fmaf(acc[5], dv, bb1.y);
  h[6] = fmaf(acc[6], dv, bb1.z);
  h[7] = fmaf(acc[7], dv, bb1.w);
  if (mode) {
    if (g == 0) {
      float4* o0 = (float4*)(out0 + (size_t)w * HID + c * 8);
      o0[0] = make_float4(h[0], h[1], h[2], h[3]);
      o0[1] = make_float4(h[4], h[5], h[6], h[7]);
      float4* o1 = (float4*)(out1 + (size_t)w * HID + c * 8);
      o1[0] = make_float4(fmaxf(h[0], 0.f), fmaxf(h[1], 0.f), fmaxf(h[2], 0.f), fmaxf(h[3], 0.f));
      o1[1] = make_float4(fmaxf(h[4], 0.f), fmaxf(h[5], 0.f), fmaxf(h[6], 0.f), fmaxf(h[7], 0.f));
    }
  } else {
    float r[8], s8 = 0.f;
#pragma unroll
    for (int i = 0; i < 8; ++i) {
      r[i] = fmaxf(h[i], 0.f);
      s8 += r[i];
    }
    float mu = wave_sum(s8) * (1.f / (HID * 4));  // cols duplicated 4x across groups
    float vs = 0.f;
#pragma unroll
    for (int i = 0; i < 8; ++i) {
      r[i] -= mu;
      vs = fmaf(r[i], r[i], vs);
    }
    float var = wave_sum(vs) * (1.f / (HID * 4));
    float sc = rsqrtf(var + LN_EPS);
    if (g == 0) {
      float4 ga0 = *(const float4*)(gamma + c * 8);
      float4 ga1 = *(const float4*)(gamma + c * 8 + 4);
      float4 be0 = *(const float4*)(beta + c * 8);
      float4 be1 = *(const float4*)(beta + c * 8 + 4);
      uint4 o;
      o.x = pack_bf2(fmaf(r[0] * sc, ga0.x, be0.x), fmaf(r[1] * sc, ga0.y, be0.y));
      o.y = pack_bf2(fmaf(r[2] * sc, ga0.z, be0.z), fmaf(r[3] * sc, ga0.w, be0.w));
      o.z = pack_bf2(fmaf(r[4] * sc, ga1.x, be1.x), fmaf(r[5] * sc, ga1.y, be1.y));
      o.w = pack_bf2(fmaf(r[6] * sc, ga1.z, be1.z), fmaf(r[7] * sc, ga1.w, be1.w));
      ((uint4*)(out_bf + (size_t)w * 64))[c] = o;
    }
  }
}

// ---- fp32 scatter fallback path (only if workspace is tiny) ----
extern "C" __global__ __launch_bounds__(256) void k_gemm(
    const float* __restrict__ x, const float* __restrict__ W,
    const float* __restrict__ dinv, float* __restrict__ g, int N) {
  __shared__ float Wl[HID * HID];
  __shared__ float xl[4][GROWS * HID];
  int tid = threadIdx.x;
#pragma unroll
  for (int i = 0; i < (HID * HID / 4) / 256; ++i)
    ((float4*)Wl)[tid + 256 * i] = ((const float4*)W)[tid + 256 * i];
  __syncthreads();
  int wid = tid >> 6, lane = tid & 63;
  float* xw = xl[wid];
  int nchunks = (N + GROWS - 1) / GROWS;
  int gw = blockIdx.x * 4 + wid;
  int nw = gridDim.x * 4;
  for (int chunk = gw; chunk < nchunks; chunk += nw) {
    int r0 = chunk * GROWS;
    int nr = min(GROWS, N - r0);
    const float4* xs = (const float4*)(x + (size_t)r0 * HID);
    float4* xd = (float4*)xw;
    if (nr == GROWS) {
#pragma unroll
      for (int i = 0; i < 4; ++i) xd[lane + 64 * i] = xs[lane + 64 * i];
    } else {
      for (int i = lane; i < nr * (HID / 4); i += 64) xd[i] = xs[i];
    }
    float2 acc[GROWS];
#pragma unroll
    for (int r = 0; r < GROWS; ++r) acc[r] = make_float2(0.f, 0.f);
    for (int k = 0; k < HID; k += 4) {
      float2 w0 = *(const float2*)&Wl[(k + 0) * HID + 2 * lane];
      float2 w1 = *(const float2*)&Wl[(k + 1) * HID + 2 * lane];
      float2 w2 = *(const float2*)&Wl[(k + 2) * HID + 2 * lane];
      float2 w3 = *(const float2*)&Wl[(k + 3) * HID + 2 * lane];
#pragma unroll
      for (int r = 0; r < GROWS; ++r) {
        float4 xq = *(const float4*)&xw[r * HID + k];
        acc[r].x = fmaf(xq.w, w3.x, fmaf(xq.z, w2.x, fmaf(xq.y, w1.x, fmaf(xq.x, w0.x, acc[r].x))));
        acc[r].y = fmaf(xq.w, w3.y, fmaf(xq.z, w2.y, fmaf(xq.y, w1.y, fmaf(xq.x, w0.y, acc[r].y))));
      }
    }
#pragma unroll
    for (int r = 0; r < GROWS; ++r) {
      if (r < nr) {
        float dv = dinv[r0 + r];
        *(float2*)(g + (size_t)(r0 + r) * HID + 2 * lane) =
            make_float2(acc[r].x * dv, acc[r].y * dv);
      }
    }
  }
}

extern "C" __global__ void k_copy(const float* __restrict__ in, float* __restrict__ out, int n4) {
  int i = blockIdx.x * blockDim.x + threadIdx.x;
  if (i < n4) ((float4*)out)[i] = ((const float4*)in)[i];
}

extern "C" __global__ void k_scatter(const float* __restrict__ g, const int* __restrict__ src,
                                     const int* __restrict__ dst, float* __restrict__ acc, int E) {
  int e = (int)((blockIdx.x * blockDim.x + threadIdx.x) >> 6);
  int lane = threadIdx.x & 63;
  if (e >= E) return;
  int s = src[e], d = dst[e];
  float2 v = *(const float2*)(g + (size_t)s * HID + 2 * lane);
  float* p = acc + (size_t)d * HID + 2 * lane;
  atomicAdd(p, v.x);
  atomicAdd(p + 1, v.y);
}

extern "C" __global__ __launch_bounds__(256) void k_fin(
    float* __restrict__ a, const float* __restrict__ dinv, const float* __restrict__ bias,
    const float* __restrict__ gamma, const float* __restrict__ beta, int N, int last) {
  int w = (int)((blockIdx.x * blockDim.x + threadIdx.x) >> 6);
  int lane = threadIdx.x & 63;
  if (w >= N) return;
  float2 acc = *(const float2*)(a + (size_t)w * HID + 2 * lane);
  float dv = dinv[w];
  float2 bb = *(const float2*)(bias + 2 * lane);
  float hx = fmaf(acc.x, dv, bb.x);
  float hy = fmaf(acc.y, dv, bb.y);
  if (last) {
    *(float2*)(a + (size_t)w * HID + 2 * lane) = make_float2(hx, hy);
  } else {
    float rx = fmaxf(hx, 0.f), ry = fmaxf(hy, 0.f);
    float mu = wave_sum(rx + ry) * (1.f / HID);
    float dx = rx - mu, dy = ry - mu;
    float var = wave_sum(dx * dx + dy * dy) * (1.f / HID);
    float sc = rsqrtf(var + LN_EPS);
    float2 ga = *(const float2*)(gamma + 2 * lane);
    float2 be = *(const float2*)(beta + 2 * lane);
    *(float2*)(a + (size_t)w * HID + 2 * lane) =
        make_float2(fmaf(dx * sc, ga.x, be.x), fmaf(dy * sc, ga.y, be.y));
  }
}

extern "C" __global__ void k_relu(const float* __restrict__ in, float* __restrict__ out, int n4) {
  int i = blockIdx.x * blockDim.x + threadIdx.x;
  if (i < n4) {
    float4 v = ((const float4*)in)[i];
    v.x = fmaxf(v.x, 0.f);
    v.y = fmaxf(v.y, 0.f);
    v.z = fmaxf(v.z, 0.f);
    v.w = fmaxf(v.w, 0.f);
    ((float4*)out)[i] = v;
  }
}

extern "C" void kernel_launch(void* const* d_in, const int* in_sizes, int n_in,
                              void* d_out, int out_size, void* d_ws, size_t ws_size,
                              hipStream_t stream) {
  const float* x0 = (const float*)d_in[0];
  const int* ei = (const int*)d_in[1];
  int N = in_sizes[0] / HID;
  int E = in_sizes[1] / 2;

  const float* W[3];
  const float* b[3];
  const float* gm[3];
  const float* bt[3];
  if (n_in >= 14 && in_sizes[2] == HID * HID) {
    for (int l = 0; l < 3; ++l) {
      W[l] = (const float*)d_in[2 + l];
      b[l] = (const float*)d_in[5 + l];
      gm[l] = (const float*)d_in[8 + l];
      bt[l] = (const float*)d_in[11 + l];
    }
  } else if (n_in >= 6) {
    const float* Wc = (const float*)d_in[2];
    const float* bc = (const float*)d_in[3];
    const float* gc = (const float*)d_in[4];
    const float* tc = (const float*)d_in[5];
    for (int l = 0; l < 3; ++l) {
      W[l] = Wc + (size_t)l * HID * HID;
      b[l] = bc + (size_t)l * HID;
      gm[l] = gc + (size_t)l * HID;
      bt[l] = tc + (size_t)l * HID;
    }
  } else {
    return;
  }
  const int* src = ei;
  const int* dst = ei + E;

  float* OUT0 = (float*)d_out;
  float* OUT1 = OUT0 + (size_t)N * HID;

  auto align256 = [](size_t bytes) { return (bytes + 255) & ~(size_t)255; };
  size_t o_cnt = 0;
  size_t o_csrc = o_cnt + align256((size_t)N * 4);
  size_t o_wt3 = o_csrc + align256((size_t)N * PDEG * 4);
  size_t o_gbf = o_wt3 + align256((size_t)3 * HID * HID * 2);
  size_t o_act = o_gbf + align256((size_t)N * 256);
  size_t need_full = o_act + (size_t)N * 256;
  size_t need_scatter = align256((size_t)N * 4);
  if (ws_size < need_scatter) return;

  char* wp = (char*)d_ws;
  int n4 = N * HID / 4;
  int aggBlocks = (N * 64 + 255) / 256;

  if (ws_size >= need_full) {
    int* cnt = (int*)(wp + o_cnt);
    int* csrc = (int*)(wp + o_csrc);
    unsigned short* wt3 = (unsigned short*)(wp + o_wt3);
    uint32* gbf = (uint32*)(wp + o_gbf);
    uint32* act = (uint32*)(wp + o_act);

    int zb = (N + 255) / 256;
    int wtb = (3 * HID * HID + 255) / 256;
    k_setup<<<zb + wtb, 256, 0, stream>>>(cnt, N, zb, W[0], W[1], W[2], wt3);
    k_fill_p<<<2048, 256, 0, stream>>>(src, dst, cnt, csrc, E, N);

    int gemmBlocks = (N + 127) / 128;
    k_gemm_t<false><<<gemmBlocks, 256, 0, stream>>>(x0, wt3, cnt, gbf, N);
    k_agg_bf<<<aggBlocks, 256, 0, stream>>>(gbf, cnt, csrc, b[0], gm[0], bt[0],
                                            act, nullptr, nullptr, N, 0);
    k_gemm_t<true><<<gemmBlocks, 256, 0, stream>>>(act, wt3 + HID * HID, cnt, gbf, N);
    k_agg_bf<<<aggBlocks, 256, 0, stream>>>(gbf, cnt, csrc, b[1], gm[1], bt[1],
                                            act, nullptr, nullptr, N, 0);
    k_gemm_t<true><<<gemmBlocks, 256, 0, stream>>>(act, wt3 + 2 * HID * HID, cnt, gbf, N);
    k_agg_bf<<<aggBlocks, 256, 0, stream>>>(gbf, cnt, csrc, b[2], gm[2], bt[2],
                                            nullptr, OUT0, OUT1, N, 3);
  } else {
    // tiny-ws fallback: fp32 scatter path
    float* dinv = (float*)wp;
    int* deg = (int*)OUT1;
    k_setup<<<(N + 255) / 256, 256, 0, stream>>>(deg, N, (N + 255) / 256,
                                                 W[0], W[1], W[2], nullptr);
    k_deg<<<(E + 255) / 256, 256, 0, stream>>>(dst, deg, E);
    k_dinv<<<(N + 255) / 256, 256, 0, stream>>>(deg, dinv, N);
    int scatBlocks = (E * 64 + 255) / 256;
    for (int l = 0; l < 3; ++l) {
      const float* xin = (l == 0) ? x0 : OUT0;
      int last = (l == 2);
      k_gemm<<<512, 256, 0, stream>>>(xin, W[l], dinv, OUT1, N);
      k_copy<<<(n4 + 255) / 256, 256, 0, stream>>>(OUT1, OUT0, n4);
      k_scatter<<<scatBlocks, 256, 0, stream>>>(OUT1, src, dst, OUT0, E);
      k_fin<<<aggBlocks, 256, 0, stream>>>(OUT0, dinv, b[l], gm[l], bt[l], N, last);
    }
    k_relu<<<(n4 + 255) / 256, 256, 0, stream>>>(OUT0, OUT1, n4);
  }
}

// Round 13
// 191.124 us; speedup vs baseline: 1.0340x; 1.0340x over previous
//
#include <hip/hip_runtime.h>
#include <cstddef>

#define HID 128
#define LN_EPS 1e-5f
#define GROWS 8
#define WTP 144   // Wt LDS row pitch in shorts: 288 B = 16B-aligned rows
#define PDEG 64   // padded CSR slots per node

typedef unsigned int uint32;
typedef __attribute__((ext_vector_type(8))) short short8;
typedef __attribute__((ext_vector_type(4))) float f32x4;

__device__ __forceinline__ float wave_sum(float v) {
#pragma unroll
  for (int o = 32; o > 0; o >>= 1) v += __shfl_xor(v, o, 64);
  return v;
}

__device__ __forceinline__ uint32 bf16_rne(float x) {
  uint32 u = __float_as_uint(x);
  u += 0x7fffu + ((u >> 16) & 1u);
  return u >> 16;
}

__device__ __forceinline__ uint32 pack_bf2(float x, float y) {
  uint32 ux = __float_as_uint(x);
  uint32 uy = __float_as_uint(y);
  ux += 0x7fffu + ((ux >> 16) & 1u);
  uy += 0x7fffu + ((uy >> 16) & 1u);
  return (ux >> 16) | (uy & 0xffff0000u);
}

__device__ __forceinline__ void acc8(float* a, uint4 u) {
  a[0] += __uint_as_float(u.x << 16);
  a[1] += __uint_as_float(u.x & 0xffff0000u);
  a[2] += __uint_as_float(u.y << 16);
  a[3] += __uint_as_float(u.y & 0xffff0000u);
  a[4] += __uint_as_float(u.z << 16);
  a[5] += __uint_as_float(u.z & 0xffff0000u);
  a[6] += __uint_as_float(u.w << 16);
  a[7] += __uint_as_float(u.w & 0xffff0000u);
}

// fused: zero cnt (first zb blocks) + transpose W->bf16 for all 3 layers
extern "C" __global__ void k_setup(int* __restrict__ cnt, int N, int zb,
                                   const float* __restrict__ W0, const float* __restrict__ W1,
                                   const float* __restrict__ W2, unsigned short* __restrict__ wt) {
  int bx = blockIdx.x;
  if (bx < zb) {
    int i = bx * 256 + threadIdx.x;
    if (i < N) cnt[i] = 0;
  } else {
    int i = (bx - zb) * 256 + threadIdx.x;
    if (i < 3 * HID * HID) {
      int l = i >> 14, r = i & 16383;
      int n = r >> 7, k = r & 127;
      const float* W = (l == 0) ? W0 : ((l == 1) ? W1 : W2);
      wt[i] = (unsigned short)bf16_rne(W[k * HID + n]);
    }
  }
}

extern "C" __global__ void k_deg(const int* __restrict__ dst, int* __restrict__ deg, int E) {
  int i = blockIdx.x * blockDim.x + threadIdx.x;
  if (i < E) atomicAdd(&deg[dst[i]], 1);
}

extern "C" __global__ void k_dinv(const int* __restrict__ cnt, float* __restrict__ dinv, int N) {
  int i = blockIdx.x * blockDim.x + threadIdx.x;
  if (i < N) dinv[i] = rsqrtf((float)cnt[i] + 1.0f);
}

// XCD-partitioned padded-CSR fill: csrc[d*PDEG + pos] = src, cnt[d]++.
extern "C" __global__ void k_fill_p(const int* __restrict__ src, const int* __restrict__ dst,
                                    int* __restrict__ cnt, int* __restrict__ csrc,
                                    int E, int N) {
  int part = blockIdx.x & 7;
  int grp = blockIdx.x >> 3;
  int ngrp = gridDim.x >> 3;
  int lo = (int)((long long)N * part >> 3);
  int hi = (int)((long long)N * (part + 1) >> 3);
  for (int i = grp * blockDim.x + threadIdx.x; i < E; i += ngrp * blockDim.x) {
    int d = dst[i];
    if (d >= lo && d < hi) {
      int pos = atomicAdd(&cnt[d], 1);
      if (pos < PDEG) csrc[(size_t)d * PDEG + pos] = src[i];
    }
  }
}

// MFMA GEMM, 64-row blocks (3.05 blocks/CU — balanced):
// gb[r][c-pair] = bf16(rsqrt(cnt[r]+1) * sum_k x[r][k]*W[k][c])
template <bool BF>
__global__ __launch_bounds__(256) void k_gemm_t(
    const void* __restrict__ xin, const unsigned short* __restrict__ wt,
    const int* __restrict__ cnt, uint32* __restrict__ gb, int N) {
  __shared__ unsigned short Wt[HID * WTP];
  __shared__ float dv_s[64];
  int tid = threadIdx.x, lane = tid & 63, wv = tid >> 6;
  int r0 = blockIdx.x * 64;
  int nr = min(64, N - r0);
  for (int i = tid; i < 2048; i += 256) {
    short8 v = *(const short8*)(wt + i * 8);
    int n = i >> 4, k0 = (i & 15) * 8;
    *(short8*)&Wt[n * WTP + k0] = v;
  }
  if (tid < 64) {
    int rr = min(r0 + tid, N - 1);
    dv_s[tid] = rsqrtf((float)cnt[rr] + 1.0f);
  }
  int arow = r0 + wv * 16 + (lane & 15);
  int arow_c = min(arow, N - 1);
  int kb = (lane >> 4) * 8;
  short8 a[4];
  if (BF) {
    const uint32* x32 = (const uint32*)xin;
    const uint32* rp = x32 + (size_t)arow_c * 64 + (kb >> 1);
#pragma unroll
    for (int q = 0; q < 4; ++q) a[q] = *(const short8*)(rp + q * 16);
  } else {
    const float* xf = (const float*)xin;
    const float* rp = xf + (size_t)arow_c * HID + kb;
#pragma unroll
    for (int q = 0; q < 4; ++q) {
      float4 f0 = *(const float4*)(rp + q * 32);
      float4 f1 = *(const float4*)(rp + q * 32 + 4);
      short8 t;
      t[0] = (short)bf16_rne(f0.x);
      t[1] = (short)bf16_rne(f0.y);
      t[2] = (short)bf16_rne(f0.z);
      t[3] = (short)bf16_rne(f0.w);
      t[4] = (short)bf16_rne(f1.x);
      t[5] = (short)bf16_rne(f1.y);
      t[6] = (short)bf16_rne(f1.z);
      t[7] = (short)bf16_rne(f1.w);
      a[q] = t;
    }
  }
  __syncthreads();
  int bn = lane & 15;
#pragma unroll
  for (int c = 0; c < 8; ++c) {
    const unsigned short* wr = &Wt[(c * 16 + bn) * WTP + kb];
    f32x4 acc = {0.f, 0.f, 0.f, 0.f};
    short8 b0 = *(const short8*)(wr + 0);
    short8 b1 = *(const short8*)(wr + 32);
    short8 b2 = *(const short8*)(wr + 64);
    short8 b3 = *(const short8*)(wr + 96);
    acc = __builtin_amdgcn_mfma_f32_16x16x32_bf16(a[0], b0, acc, 0, 0, 0);
    acc = __builtin_amdgcn_mfma_f32_16x16x32_bf16(a[1], b1, acc, 0, 0, 0);
    acc = __builtin_amdgcn_mfma_f32_16x16x32_bf16(a[2], b2, acc, 0, 0, 0);
    acc = __builtin_amdgcn_mfma_f32_16x16x32_bf16(a[3], b3, acc, 0, 0, 0);
#pragma unroll
    for (int reg = 0; reg < 4; ++reg) {
      float v = acc[reg];
      float p = __shfl_xor(v, 1, 64);
      int row = wv * 16 + (lane >> 4) * 4 + reg;
      if (!(lane & 1) && row < nr) {
        float dvv = dv_s[row];
        gb[(size_t)(r0 + row) * 64 + (c * 8 + (bn >> 1))] = pack_bf2(v * dvv, p * dvv);
      }
    }
  }
}

// wide-gather agg: idx-prefetch + MLP-4 16-blocks + dual-load 8-block + 4-block + tail.
// wave = 1 node, 4 groups x 16 lanes; lane preloads csrc[w*64+lane];
// mode 0: out_bf = packed bf16 LN(relu(h)); mode 3: out0 = h fp32, out1 = relu(h) fp32
extern "C" __global__ __launch_bounds__(256) void k_agg_bf(
    const uint32* __restrict__ gb, const int* __restrict__ cnt, const int* __restrict__ csrc,
    const float* __restrict__ bias, const float* __restrict__ gamma,
    const float* __restrict__ beta,
    uint32* __restrict__ out_bf, float* __restrict__ out0, float* __restrict__ out1,
    int N, int mode) {
  int w = (int)((blockIdx.x * blockDim.x + threadIdx.x) >> 6);
  int lane = threadIdx.x & 63;
  if (w >= N) return;
  int g = lane >> 4, c = lane & 15;
  int rawdeg = cnt[w];
  int deg = min(rawdeg, PDEG);
  int myidx = (lane < deg) ? csrc[(size_t)w * PDEG + lane] : 0;
  const uint4* gbp = (const uint4*)gb;  // row r chunk c at [r*16 + c]
  float accA[8], accB[8];
  {  // self term, counted once (group 0) -> A; B zeroed
    uint4 u = gbp[(size_t)w * 16 + c];
    float m = (g == 0) ? 1.f : 0.f;
    accA[0] = m * __uint_as_float(u.x << 16);
    accA[1] = m * __uint_as_float(u.x & 0xffff0000u);
    accA[2] = m * __uint_as_float(u.y << 16);
    accA[3] = m * __uint_as_float(u.y & 0xffff0000u);
    accA[4] = m * __uint_as_float(u.z << 16);
    accA[5] = m * __uint_as_float(u.z & 0xffff0000u);
    accA[6] = m * __uint_as_float(u.w << 16);
    accA[7] = m * __uint_as_float(u.w & 0xffff0000u);
#pragma unroll
    for (int i = 0; i < 8; ++i) accB[i] = 0.f;
  }
  int j = 0;
  for (; j + 16 <= deg; j += 16) {
    int s0 = __shfl(myidx, j + g, 64);
    int s1 = __shfl(myidx, j + 4 + g, 64);
    int s2 = __shfl(myidx, j + 8 + g, 64);
    int s3 = __shfl(myidx, j + 12 + g, 64);
    uint4 u0 = gbp[(size_t)s0 * 16 + c];
    uint4 u1 = gbp[(size_t)s1 * 16 + c];
    uint4 u2 = gbp[(size_t)s2 * 16 + c];
    uint4 u3 = gbp[(size_t)s3 * 16 + c];
    acc8(accA, u0);
    acc8(accB, u1);
    acc8(accA, u2);
    acc8(accB, u3);
  }
  if (j + 8 <= deg) {  // 8-edge block: two independent loads in flight
    int s0 = __shfl(myidx, j + g, 64);
    int s1 = __shfl(myidx, j + 4 + g, 64);
    uint4 u0 = gbp[(size_t)s0 * 16 + c];
    uint4 u1 = gbp[(size_t)s1 * 16 + c];
    acc8(accA, u0);
    acc8(accB, u1);
    j += 8;
  }
  if (j + 4 <= deg) {
    int s = __shfl(myidx, j + g, 64);
    uint4 u = gbp[(size_t)s * 16 + c];
    acc8(accA, u);
    j += 4;
  }
  if (j < deg) {  // wave-uniform entry: shfl runs with ALL lanes active
    int s = __shfl(myidx, j + g, 64);
    if (g < deg - j) {  // only the load/acc is masked
      uint4 u = gbp[(size_t)s * 16 + c];
      acc8(accB, u);
    }
  }
  float acc[8];
#pragma unroll
  for (int i = 0; i < 8; ++i) acc[i] = accA[i] + accB[i];
  // cross-group reduce: every lane then holds full sums for its 8 cols
#pragma unroll
  for (int i = 0; i < 8; ++i) {
    acc[i] += __shfl_xor(acc[i], 16, 64);
    acc[i] += __shfl_xor(acc[i], 32, 64);
  }
  float dv = rsqrtf((float)rawdeg + 1.0f);
  float4 bb0 = *(const float4*)(bias + c * 8);
  float4 bb1 = *(const float4*)(bias + c * 8 + 4);
  float h[8];
  h[0] = fmaf(acc[0], dv, bb0.x);
  h[1] = fmaf(acc[1], dv, bb0.y);
  h[2] = fmaf(acc[2], dv, bb0.z);
  h[3] = fmaf(acc[3], dv, bb0.w);
  h[4] = fmaf(acc[4], dv, bb1.x);
  h[5] = fmaf(acc[5], dv, bb1.y);
  h[6] = fmaf(acc[6], dv, bb1.z);
  h[7] = fmaf(acc[7], dv, bb1.w);
  if (mode) {
    if (g == 0) {
      float4* o0 = (float4*)(out0 + (size_t)w * HID + c * 8);
      o0[0] = make_float4(h[0], h[1], h[2], h[3]);
      o0[1] = make_float4(h[4], h[5], h[6], h[7]);
      float4* o1 = (float4*)(out1 + (size_t)w * HID + c * 8);
      o1[0] = make_float4(fmaxf(h[0], 0.f), fmaxf(h[1], 0.f), fmaxf(h[2], 0.f), fmaxf(h[3], 0.f));
      o1[1] = make_float4(fmaxf(h[4], 0.f), fmaxf(h[5], 0.f), fmaxf(h[6], 0.f), fmaxf(h[7], 0.f));
    }
  } else {
    float r[8], s8 = 0.f;
#pragma unroll
    for (int i = 0; i < 8; ++i) {
      r[i] = fmaxf(h[i], 0.f);
      s8 += r[i];
    }
    float mu = wave_sum(s8) * (1.f / (HID * 4));  // cols duplicated 4x across groups
    float vs = 0.f;
#pragma unroll
    for (int i = 0; i < 8; ++i) {
      r[i] -= mu;
      vs = fmaf(r[i], r[i], vs);
    }
    float var = wave_sum(vs) * (1.f / (HID * 4));
    float sc = rsqrtf(var + LN_EPS);
    if (g == 0) {
      float4 ga0 = *(const float4*)(gamma + c * 8);
      float4 ga1 = *(const float4*)(gamma + c * 8 + 4);
      float4 be0 = *(const float4*)(beta + c * 8);
      float4 be1 = *(const float4*)(beta + c * 8 + 4);
      uint4 o;
      o.x = pack_bf2(fmaf(r[0] * sc, ga0.x, be0.x), fmaf(r[1] * sc, ga0.y, be0.y));
      o.y = pack_bf2(fmaf(r[2] * sc, ga0.z, be0.z), fmaf(r[3] * sc, ga0.w, be0.w));
      o.z = pack_bf2(fmaf(r[4] * sc, ga1.x, be1.x), fmaf(r[5] * sc, ga1.y, be1.y));
      o.w = pack_bf2(fmaf(r[6] * sc, ga1.z, be1.z), fmaf(r[7] * sc, ga1.w, be1.w));
      ((uint4*)(out_bf + (size_t)w * 64))[c] = o;
    }
  }
}

// ---- fp32 scatter fallback path (only if workspace is tiny) ----
extern "C" __global__ __launch_bounds__(256) void k_gemm(
    const float* __restrict__ x, const float* __restrict__ W,
    const float* __restrict__ dinv, float* __restrict__ g, int N) {
  __shared__ float Wl[HID * HID];
  __shared__ float xl[4][GROWS * HID];
  int tid = threadIdx.x;
#pragma unroll
  for (int i = 0; i < (HID * HID / 4) / 256; ++i)
    ((float4*)Wl)[tid + 256 * i] = ((const float4*)W)[tid + 256 * i];
  __syncthreads();
  int wid = tid >> 6, lane = tid & 63;
  float* xw = xl[wid];
  int nchunks = (N + GROWS - 1) / GROWS;
  int gw = blockIdx.x * 4 + wid;
  int nw = gridDim.x * 4;
  for (int chunk = gw; chunk < nchunks; chunk += nw) {
    int r0 = chunk * GROWS;
    int nr = min(GROWS, N - r0);
    const float4* xs = (const float4*)(x + (size_t)r0 * HID);
    float4* xd = (float4*)xw;
    if (nr == GROWS) {
#pragma unroll
      for (int i = 0; i < 4; ++i) xd[lane + 64 * i] = xs[lane + 64 * i];
    } else {
      for (int i = lane; i < nr * (HID / 4); i += 64) xd[i] = xs[i];
    }
    float2 acc[GROWS];
#pragma unroll
    for (int r = 0; r < GROWS; ++r) acc[r] = make_float2(0.f, 0.f);
    for (int k = 0; k < HID; k += 4) {
      float2 w0 = *(const float2*)&Wl[(k + 0) * HID + 2 * lane];
      float2 w1 = *(const float2*)&Wl[(k + 1) * HID + 2 * lane];
      float2 w2 = *(const float2*)&Wl[(k + 2) * HID + 2 * lane];
      float2 w3 = *(const float2*)&Wl[(k + 3) * HID + 2 * lane];
#pragma unroll
      for (int r = 0; r < GROWS; ++r) {
        float4 xq = *(const float4*)&xw[r * HID + k];
        acc[r].x = fmaf(xq.w, w3.x, fmaf(xq.z, w2.x, fmaf(xq.y, w1.x, fmaf(xq.x, w0.x, acc[r].x))));
        acc[r].y = fmaf(xq.w, w3.y, fmaf(xq.z, w2.y, fmaf(xq.y, w1.y, fmaf(xq.x, w0.y, acc[r].y))));
      }
    }
#pragma unroll
    for (int r = 0; r < GROWS; ++r) {
      if (r < nr) {
        float dv = dinv[r0 + r];
        *(float2*)(g + (size_t)(r0 + r) * HID + 2 * lane) =
            make_float2(acc[r].x * dv, acc[r].y * dv);
      }
    }
  }
}

extern "C" __global__ void k_copy(const float* __restrict__ in, float* __restrict__ out, int n4) {
  int i = blockIdx.x * blockDim.x + threadIdx.x;
  if (i < n4) ((float4*)out)[i] = ((const float4*)in)[i];
}

extern "C" __global__ void k_scatter(const float* __restrict__ g, const int* __restrict__ src,
                                     const int* __restrict__ dst, float* __restrict__ acc, int E) {
  int e = (int)((blockIdx.x * blockDim.x + threadIdx.x) >> 6);
  int lane = threadIdx.x & 63;
  if (e >= E) return;
  int s = src[e], d = dst[e];
  float2 v = *(const float2*)(g + (size_t)s * HID + 2 * lane);
  float* p = acc + (size_t)d * HID + 2 * lane;
  atomicAdd(p, v.x);
  atomicAdd(p + 1, v.y);
}

extern "C" __global__ __launch_bounds__(256) void k_fin(
    float* __restrict__ a, const float* __restrict__ dinv, const float* __restrict__ bias,
    const float* __restrict__ gamma, const float* __restrict__ beta, int N, int last) {
  int w = (int)((blockIdx.x * blockDim.x + threadIdx.x) >> 6);
  int lane = threadIdx.x & 63;
  if (w >= N) return;
  float2 acc = *(const float2*)(a + (size_t)w * HID + 2 * lane);
  float dv = dinv[w];
  float2 bb = *(const float2*)(bias + 2 * lane);
  float hx = fmaf(acc.x, dv, bb.x);
  float hy = fmaf(acc.y, dv, bb.y);
  if (last) {
    *(float2*)(a + (size_t)w * HID + 2 * lane) = make_float2(hx, hy);
  } else {
    float rx = fmaxf(hx, 0.f), ry = fmaxf(hy, 0.f);
    float mu = wave_sum(rx + ry) * (1.f / HID);
    float dx = rx - mu, dy = ry - mu;
    float var = wave_sum(dx * dx + dy * dy) * (1.f / HID);
    float sc = rsqrtf(var + LN_EPS);
    float2 ga = *(const float2*)(gamma + 2 * lane);
    float2 be = *(const float2*)(beta + 2 * lane);
    *(float2*)(a + (size_t)w * HID + 2 * lane) =
        make_float2(fmaf(dx * sc, ga.x, be.x), fmaf(dy * sc, ga.y, be.y));
  }
}

extern "C" __global__ void k_relu(const float* __restrict__ in, float* __restrict__ out, int n4) {
  int i = blockIdx.x * blockDim.x + threadIdx.x;
  if (i < n4) {
    float4 v = ((const float4*)in)[i];
    v.x = fmaxf(v.x, 0.f);
    v.y = fmaxf(v.y, 0.f);
    v.z = fmaxf(v.z, 0.f);
    v.w = fmaxf(v.w, 0.f);
    ((float4*)out)[i] = v;
  }
}

extern "C" void kernel_launch(void* const* d_in, const int* in_sizes, int n_in,
                              void* d_out, int out_size, void* d_ws, size_t ws_size,
                              hipStream_t stream) {
  const float* x0 = (const float*)d_in[0];
  const int* ei = (const int*)d_in[1];
  int N = in_sizes[0] / HID;
  int E = in_sizes[1] / 2;

  const float* W[3];
  const float* b[3];
  const float* gm[3];
  const float* bt[3];
  if (n_in >= 14 && in_sizes[2] == HID * HID) {
    for (int l = 0; l < 3; ++l) {
      W[l] = (const float*)d_in[2 + l];
      b[l] = (const float*)d_in[5 + l];
      gm[l] = (const float*)d_in[8 + l];
      bt[l] = (const float*)d_in[11 + l];
    }
  } else if (n_in >= 6) {
    const float* Wc = (const float*)d_in[2];
    const float* bc = (const float*)d_in[3];
    const float* gc = (const float*)d_in[4];
    const float* tc = (const float*)d_in[5];
    for (int l = 0; l < 3; ++l) {
      W[l] = Wc + (size_t)l * HID * HID;
      b[l] = bc + (size_t)l * HID;
      gm[l] = gc + (size_t)l * HID;
      bt[l] = tc + (size_t)l * HID;
    }
  } else {
    return;
  }
  const int* src = ei;
  const int* dst = ei + E;

  float* OUT0 = (float*)d_out;
  float* OUT1 = OUT0 + (size_t)N * HID;

  auto align256 = [](size_t bytes) { return (bytes + 255) & ~(size_t)255; };
  size_t o_cnt = 0;
  size_t o_csrc = o_cnt + align256((size_t)N * 4);
  size_t o_wt3 = o_csrc + align256((size_t)N * PDEG * 4);
  size_t o_gbf = o_wt3 + align256((size_t)3 * HID * HID * 2);
  size_t o_act = o_gbf + align256((size_t)N * 256);
  size_t need_full = o_act + (size_t)N * 256;
  size_t need_scatter = align256((size_t)N * 4);
  if (ws_size < need_scatter) return;

  char* wp = (char*)d_ws;
  int n4 = N * HID / 4;
  int aggBlocks = (N * 64 + 255) / 256;

  if (ws_size >= need_full) {
    int* cnt = (int*)(wp + o_cnt);
    int* csrc = (int*)(wp + o_csrc);
    unsigned short* wt3 = (unsigned short*)(wp + o_wt3);
    uint32* gbf = (uint32*)(wp + o_gbf);
    uint32* act = (uint32*)(wp + o_act);

    int zb = (N + 255) / 256;
    int wtb = (3 * HID * HID + 255) / 256;
    k_setup<<<zb + wtb, 256, 0, stream>>>(cnt, N, zb, W[0], W[1], W[2], wt3);
    k_fill_p<<<2048, 256, 0, stream>>>(src, dst, cnt, csrc, E, N);

    int gemmBlocks = (N + 63) / 64;
    k_gemm_t<false><<<gemmBlocks, 256, 0, stream>>>(x0, wt3, cnt, gbf, N);
    k_agg_bf<<<aggBlocks, 256, 0, stream>>>(gbf, cnt, csrc, b[0], gm[0], bt[0],
                                            act, nullptr, nullptr, N, 0);
    k_gemm_t<true><<<gemmBlocks, 256, 0, stream>>>(act, wt3 + HID * HID, cnt, gbf, N);
    k_agg_bf<<<aggBlocks, 256, 0, stream>>>(gbf, cnt, csrc, b[1], gm[1], bt[1],
                                            act, nullptr, nullptr, N, 0);
    k_gemm_t<true><<<gemmBlocks, 256, 0, stream>>>(act, wt3 + 2 * HID * HID, cnt, gbf, N);
    k_agg_bf<<<aggBlocks, 256, 0, stream>>>(gbf, cnt, csrc, b[2], gm[2], bt[2],
                                            nullptr, OUT0, OUT1, N, 3);
  } else {
    // tiny-ws fallback: fp32 scatter path
    float* dinv = (float*)wp;
    int* deg = (int*)OUT1;
    k_setup<<<(N + 255) / 256, 256, 0, stream>>>(deg, N, (N + 255) / 256,
                                                 W[0], W[1], W[2], nullptr);
    k_deg<<<(E + 255) / 256, 256, 0, stream>>>(dst, deg, E);
    k_dinv<<<(N + 255) / 256, 256, 0, stream>>>(deg, dinv, N);
    int scatBlocks = (E * 64 + 255) / 256;
    for (int l = 0; l < 3; ++l) {
      const float* xin = (l == 0) ? x0 : OUT0;
      int last = (l == 2);
      k_gemm<<<512, 256, 0, stream>>>(xin, W[l], dinv, OUT1, N);
      k_copy<<<(n4 + 255) / 256, 256, 0, stream>>>(OUT1, OUT0, n4);
      k_scatter<<<scatBlocks, 256, 0, stream>>>(OUT1, src, dst, OUT0, E);
      k_fin<<<aggBlocks, 256, 0, stream>>>(OUT0, dinv, b[l], gm[l], bt[l], N, last);
    }
    k_relu<<<(n4 + 255) / 256, 256, 0, stream>>>(OUT0, OUT1, n4);
  }
}